// Round 11
// baseline (5659.258 us; speedup 1.0000x reference)
//
#include <hip/hip_runtime.h>
#include <hip/hip_bf16.h>
#include <stdint.h>

// a3c_lstm_ga forward, MI355X. Float tensors f32 (bf16-rounded values), ints
// int32. Output f32: [critic(1), actor(4), hx_new(768), cx_new(768)].
// Bug-faithful: only attn[0] consumed -> one GRU scan.
//
// R11: BARRIER-FREE flag-pipelined MFMA scan. R6-R8 lockstep barrier scans
// all plateau at ~2700-2800 cyc/step = 1536 MFMA-issue floor + ~1200 fully
// exposed serial bubble (gates+barriers, matrix pipe idle). Gate-aligned
// layout (R8) means K-tile kt consumes exactly h-chunk kt = wave kt's
// product. So: per-chunk LDS flags (release/acquire, workgroup scope)
// replace both barriers; each wave walks K-tiles in rotated order starting
// at its OWN chunk (no wait), B-frags packed in rotated K order at init so
// register names stay static. Max skew transitively bounded at 1 step ->
// parity double-buffer is safe. SIMD-partner waves now fill each other's
// gate-phase bubbles (m114 co-scheduling).
// h rides A rows 0/1 (hi, (h-hi)*1024); y = D[0][n] + D[1][n]/1024.
// R10 learnings kept: VALU-path hybrid dead (dot2 needs true VGPRs, budget
// 128); conv tower as block 1 of scan grid; inline f32->f16 B-pack.

typedef _Float16 half8 __attribute__((ext_vector_type(8)));
typedef _Float16 half2v __attribute__((ext_vector_type(2)));
typedef float f32x4 __attribute__((ext_vector_type(4)));

__device__ __forceinline__ float sigm(float x) { return 1.0f / (1.0f + __expf(-x)); }
__device__ __forceinline__ float tanh_f(float x) { return 2.0f / (1.0f + __expf(-2.0f * x)) - 1.0f; }
__device__ __forceinline__ uint32_t pk(float a, float b) {
    half2v h = {(_Float16)a, (_Float16)b};
    return __builtin_bit_cast(uint32_t, h);
}

// ---------------- GRU input-gate precompute (+ b_hh fold for r,z rows) ---------
__global__ void k_gi(const int* __restrict__ curr, const float* __restrict__ emb,
                     const float* __restrict__ wih, const float* __restrict__ bih,
                     const float* __restrict__ bhh, float* __restrict__ gi) {
    int idx = blockIdx.x * 256 + threadIdx.x;  // 2048*768
    int j = idx % 768, t = idx / 768;
    int tok = curr[t];
    const float4* e = (const float4*)(emb + tok * 32);
    const float4* wr = (const float4*)(wih + j * 32);
    float acc = bih[j] + (j < 512 ? bhh[j] : 0.0f);  // n-row bias NOT additive (r*b)
#pragma unroll
    for (int k = 0; k < 8; ++k) {
        float4 ev = e[k], wv = wr[k];
        acc = fmaf(ev.x, wv.x, acc);
        acc = fmaf(ev.y, wv.y, acc);
        acc = fmaf(ev.z, wv.z, acc);
        acc = fmaf(ev.w, wv.w, acc);
    }
    gi[idx] = acc;
}

// ---------------- scan (block 0) + conv tower (block 1) ----------------
#define PACK8(dst, p)                                   \
    {                                                   \
        float4 fA = *(const float4*)(p);                \
        float4 fB = *(const float4*)((p) + 4);          \
        dst.x = pk(fA.x, fA.y); dst.y = pk(fA.z, fA.w); \
        dst.z = pk(fB.x, fB.y); dst.w = pk(fB.z, fB.w); \
    }
// tile T's frag for SLOT i packs K-chunk (wv+i)&7 -> loop uses static names
#define PACKT(u0, u1, u2, u3, u4, u5, u6, u7, rp)                  \
    PACK8(u0, (rp) + ko0 + quad * 8) PACK8(u1, (rp) + ko1 + quad * 8) \
    PACK8(u2, (rp) + ko2 + quad * 8) PACK8(u3, (rp) + ko3 + quad * 8) \
    PACK8(u4, (rp) + ko4 + quad * 8) PACK8(u5, (rp) + ko5 + quad * 8) \
    PACK8(u6, (rp) + ko6 + quad * 8) PACK8(u7, (rp) + ko7 + quad * 8)
#define TIE1(v) asm volatile("" : "+v"(v.x), "+v"(v.y), "+v"(v.z), "+v"(v.w));
#define MM(A, B, C) __builtin_amdgcn_mfma_f32_16x16x32_f16(A, __builtin_bit_cast(half8, B), C, 0, 0, 0)
#define MF6(A, u0, u1, u2, u3, u4, u5)              \
    acc0 = MM(A, u0, acc0); acc1 = MM(A, u1, acc1); \
    acc2 = MM(A, u2, acc2); acc3 = MM(A, u3, acc3); \
    acc4 = MM(A, u4, acc4); acc5 = MM(A, u5, acc5);
#define SPIN(k)                                                              \
    while (__hip_atomic_load(&flg[k], __ATOMIC_ACQUIRE,                      \
                             __HIP_MEMORY_SCOPE_WORKGROUP) < step) {}

__global__ __attribute__((amdgpu_flat_work_group_size(512, 512), amdgpu_waves_per_eu(2, 2)))
void k_scan(const float* __restrict__ gi, const float* __restrict__ whh,
            const float* __restrict__ bhh, const float* __restrict__ attn_w,
            const float* __restrict__ attn_b, float* __restrict__ attn0,
            const float* __restrict__ x, const float* __restrict__ c1w,
            const float* __restrict__ c1b, const float* __restrict__ c2w,
            const float* __restrict__ c2b, const float* __restrict__ c3w,
            const float* __restrict__ c3b, float* __restrict__ h1,
            float* __restrict__ h2, float* __restrict__ x3) {
    const int bid = blockIdx.x;
    const int tid = threadIdx.x;  // 0..511

    if (bid == 1) {  // ---- conv tower on a second CU, runs under the scan ----
        for (int it = 0; it < 225; ++it) {
            int idx = it * 512 + tid;
            int ox = idx % 30, oy = (idx / 30) % 30, oc = idx / 900;
            const float* wr = c1w + oc * 192;
            float acc = c1b[oc];
            for (int c = 0; c < 3; ++c)
                for (int ky = 0; ky < 8; ++ky) {
                    const float* xr = x + (c * 124 + oy * 4 + ky) * 124 + ox * 4;
                    const float* wk = wr + (c * 8 + ky) * 8;
#pragma unroll
                    for (int kx = 0; kx < 8; ++kx) acc = fmaf(xr[kx], wk[kx], acc);
                }
            h1[idx] = fmaxf(acc, 0.0f);
        }
        __syncthreads();
        for (int it = 0; it < 25; ++it) {
            int idx = it * 512 + tid;
            if (idx < 12544) {
                int ox = idx % 14, oy = (idx / 14) % 14, oc = idx / 196;
                float acc = c2b[oc];
                const float* wr = c2w + oc * 128 * 16;
                for (int c = 0; c < 128; ++c) {
#pragma unroll
                    for (int ky = 0; ky < 4; ++ky) {
                        const float* hr = h1 + (c * 30 + oy * 2 + ky) * 30 + ox * 2;
                        const float* wk = wr + (c * 4 + ky) * 4;
#pragma unroll
                        for (int kx = 0; kx < 4; ++kx) acc = fmaf(hr[kx], wk[kx], acc);
                    }
                }
                h2[idx] = fmaxf(acc, 0.0f);
            }
        }
        __syncthreads();
        for (int it = 0; it < 5; ++it) {
            int idx = it * 512 + tid;
            if (idx < 2304) {
                int ox = idx % 6, oy = (idx / 6) % 6, oc = idx / 36;
                float acc = c3b[oc];
                const float* wr = c3w + oc * 64 * 16;
                for (int c = 0; c < 64; ++c) {
#pragma unroll
                    for (int ky = 0; ky < 4; ++ky) {
                        const float* hr = h2 + (c * 14 + oy * 2 + ky) * 14 + ox * 2;
                        const float* wk = wr + (c * 4 + ky) * 4;
#pragma unroll
                        for (int kx = 0; kx < 4; ++kx) acc = fmaf(hr[kx], wk[kx], acc);
                    }
                }
                x3[idx] = fmaxf(acc, 0.0f);
            }
        }
        return;
    }
    if (bid != 0) return;

    // ---- flag-pipelined scan, one CU ----
    const int lane = tid & 63;
    const int wv = tid >> 6;     // wave 0..7 owns elements [wv*32, wv*32+32) = chunk wv
    const int n16 = lane & 15;   // B row-in-tile; A row m; gate col
    const int quad = lane >> 4;  // k-subchunk

    // parity-double-buffered h: parity p at f16 [p*512,+512); chunk c = hi[32]+lo[32]
    __shared__ __align__(16) _Float16 hbuf[1024];
    __shared__ int flg[8];  // flg[c] = s  <=>  h(s) of chunk c is published

    // rotated K-slot order: slot i handles K-chunk (wv+i)&7 (own chunk first)
    const int kt1 = (wv + 1) & 7, kt2 = (wv + 2) & 7, kt3 = (wv + 3) & 7;
    const int kt4 = (wv + 4) & 7, kt5 = (wv + 5) & 7, kt6 = (wv + 6) & 7;
    const int kt7 = (wv + 7) & 7;
    const int ko0 = wv * 32, ko1 = kt1 * 32, ko2 = kt2 * 32, ko3 = kt3 * 32;
    const int ko4 = kt4 * 32, ko5 = kt5 * 32, ko6 = kt6 * 32, ko7 = kt7 * 32;

    // B-frags (f16, exact for bf16-rounded data): 6 tiles x 8 slots = 48 uint4
    uint4 U0, U1, U2, U3, U4, U5, U6, U7, U8, U9, U10, U11, U12, U13, U14, U15;
    uint4 U16, U17, U18, U19, U20, U21, U22, U23, U24, U25, U26, U27, U28, U29, U30, U31;
    uint4 U32, U33, U34, U35, U36, U37, U38, U39, U40, U41, U42, U43, U44, U45, U46, U47;
    {
        const float* rp0 = whh + (size_t)(wv * 32 + n16) * 256;         // r
        const float* rp1 = whh + (size_t)(wv * 32 + 16 + n16) * 256;    // r
        const float* rp2 = whh + (size_t)(256 + wv * 32 + n16) * 256;   // z
        const float* rp3 = whh + (size_t)(256 + wv * 32 + 16 + n16) * 256;
        const float* rp4 = whh + (size_t)(512 + wv * 32 + n16) * 256;   // n
        const float* rp5 = whh + (size_t)(512 + wv * 32 + 16 + n16) * 256;
        PACKT(U0, U1, U2, U3, U4, U5, U6, U7, rp0)
        PACKT(U8, U9, U10, U11, U12, U13, U14, U15, rp1)
        PACKT(U16, U17, U18, U19, U20, U21, U22, U23, rp2)
        PACKT(U24, U25, U26, U27, U28, U29, U30, U31, rp3)
        PACKT(U32, U33, U34, U35, U36, U37, U38, U39, rp4)
        PACKT(U40, U41, U42, U43, U44, U45, U46, U47, rp5)
    }
    TIE1(U0) TIE1(U1) TIE1(U2) TIE1(U3) TIE1(U4) TIE1(U5) TIE1(U6) TIE1(U7)
    TIE1(U8) TIE1(U9) TIE1(U10) TIE1(U11) TIE1(U12) TIE1(U13) TIE1(U14) TIE1(U15)
    TIE1(U16) TIE1(U17) TIE1(U18) TIE1(U19) TIE1(U20) TIE1(U21) TIE1(U22) TIE1(U23)
    TIE1(U24) TIE1(U25) TIE1(U26) TIE1(U27) TIE1(U28) TIE1(U29) TIE1(U30) TIE1(U31)
    TIE1(U32) TIE1(U33) TIE1(U34) TIE1(U35) TIE1(U36) TIE1(U37) TIE1(U38) TIE1(U39)
    TIE1(U40) TIE1(U41) TIE1(U42) TIE1(U43) TIE1(U44) TIE1(U45) TIE1(U46) TIE1(U47)

    // per-lane gate state (valid in lanes 0-15)
    const float bn0 = bhh[512 + wv * 32 + n16];
    const float bn1 = bhh[512 + wv * 32 + 16 + n16];
    float gr0 = 0.f, gr1 = 0.f, gz0 = 0.f, gz1 = 0.f, gn0 = 0.f, gn1 = 0.f;
    if (lane < 16) {
        const float* g0 = gi + wv * 32 + n16;
        gr0 = g0[0]; gr1 = g0[16]; gz0 = g0[256]; gz1 = g0[272];
        gn0 = g0[512]; gn1 = g0[528];
    }
    float h0 = 0.0f, h1r = 0.0f;
    hbuf[tid] = (_Float16)0.0f;
    hbuf[512 + tid] = (_Float16)0.0f;
    if (tid < 8) flg[tid] = 0;
    __syncthreads();  // the only barrier

#pragma clang loop unroll(disable)
    for (int step = 0; step < 2048; ++step) {
        const int par = step & 1;
        const uint4* ab = (const uint4*)hbuf + par * 64 + ((n16 == 1) ? 4 : 0);

        // slot 0 = own chunk: no wait (own release drained our prior write)
        half8 aC = __builtin_bit_cast(half8, ab[wv * 8 + quad]);
        SPIN(kt1)
        half8 aN = __builtin_bit_cast(half8, ab[kt1 * 8 + quad]);

        // gi prefetch; latency hides under MFMAs
        float pr0 = 0.f, pr1 = 0.f, pz0 = 0.f, pz1 = 0.f, pn0 = 0.f, pn1 = 0.f;
        if (step < 2047 && lane < 16) {
            const float* gp = gi + (size_t)(step + 1) * 768 + wv * 32 + n16;
            pr0 = gp[0]; pr1 = gp[16]; pz0 = gp[256]; pz1 = gp[272];
            pn0 = gp[512]; pn1 = gp[528];
        }

        f32x4 acc0 = (f32x4)(0.f), acc1 = (f32x4)(0.f), acc2 = (f32x4)(0.f);
        f32x4 acc3 = (f32x4)(0.f), acc4 = (f32x4)(0.f), acc5 = (f32x4)(0.f);
        MF6(aC, U0, U8, U16, U24, U32, U40)
        SPIN(kt2) aC = __builtin_bit_cast(half8, ab[kt2 * 8 + quad]);
        MF6(aN, U1, U9, U17, U25, U33, U41)
        SPIN(kt3) aN = __builtin_bit_cast(half8, ab[kt3 * 8 + quad]);
        MF6(aC, U2, U10, U18, U26, U34, U42)
        SPIN(kt4) aC = __builtin_bit_cast(half8, ab[kt4 * 8 + quad]);
        MF6(aN, U3, U11, U19, U27, U35, U43)
        SPIN(kt5) aN = __builtin_bit_cast(half8, ab[kt5 * 8 + quad]);
        MF6(aC, U4, U12, U20, U28, U36, U44)
        SPIN(kt6) aC = __builtin_bit_cast(half8, ab[kt6 * 8 + quad]);
        MF6(aN, U5, U13, U21, U29, U37, U45)
        SPIN(kt7) aN = __builtin_bit_cast(half8, ab[kt7 * 8 + quad]);
        MF6(aC, U6, U14, U22, U30, U38, U46)
        MF6(aN, U7, U15, U23, U31, U39, U47)

        // in-register gates: lane<16 holds cols of this wave's 6 tiles
        if (lane < 16) {
            const float SC = 0.0009765625f;  // 2^-10
            float yr0 = fmaf(acc0.y, SC, acc0.x);
            float yr1 = fmaf(acc1.y, SC, acc1.x);
            float yz0 = fmaf(acc2.y, SC, acc2.x);
            float yz1 = fmaf(acc3.y, SC, acc3.x);
            float yn0 = fmaf(acc4.y, SC, acc4.x) + bn0;
            float yn1 = fmaf(acc5.y, SC, acc5.x) + bn1;
            float r0 = sigm(gr0 + yr0), r1 = sigm(gr1 + yr1);
            float z0 = sigm(gz0 + yz0), z1 = sigm(gz1 + yz1);
            float n0 = tanh_f(fmaf(r0, yn0, gn0));
            float n1 = tanh_f(fmaf(r1, yn1, gn1));
            h0 = fmaf(z0, h0 - n0, n0);  // (1-z)*n + z*h
            h1r = fmaf(z1, h1r - n1, n1);
            int wb = ((step + 1) & 1) * 512 + wv * 64;
            _Float16 h0h = (_Float16)h0, h1h = (_Float16)h1r;
            hbuf[wb + n16] = h0h;
            hbuf[wb + 32 + n16] = (_Float16)((h0 - (float)h0h) * 1024.0f);
            hbuf[wb + 16 + n16] = h1h;
            hbuf[wb + 48 + n16] = (_Float16)((h1r - (float)h1h) * 1024.0f);
        }
        gr0 = pr0; gr1 = pr1; gz0 = pz0; gz1 = pz1; gn0 = pn0; gn1 = pn1;
        // release: waits the wave's h ds_writes, then publishes
        if (lane == 0)
            __hip_atomic_store(&flg[wv], step + 1, __ATOMIC_RELEASE,
                               __HIP_MEMORY_SCOPE_WORKGROUP);
    }

    // attention head: attn0[j] = sigm(attn_w[j] . h + attn_b[j]), j<64; h(2048)
    // lives in parity-0 buffer. Wave 0 waits for all chunks' final publish.
    if (tid < 64) {
        for (int c = 0; c < 8; ++c)
            while (__hip_atomic_load(&flg[c], __ATOMIC_ACQUIRE,
                                     __HIP_MEMORY_SCOPE_WORKGROUP) < 2048) {}
        const float* ar = attn_w + tid * 256;
        float acc = attn_b[tid];
        for (int k = 0; k < 256; ++k) {
            int c = k >> 5, i = k & 31;
            float hk = (float)hbuf[c * 64 + i] + (float)hbuf[c * 64 + 32 + i] * 0.0009765625f;
            acc = fmaf(ar[k], hk, acc);
        }
        attn0[tid] = sigm(acc);
    }
}

// ---------------- fuse + linear ----------------
__global__ void k_feat(const float* __restrict__ x3, const float* __restrict__ attn0,
                       const float* __restrict__ lw, const float* __restrict__ lb,
                       float* __restrict__ feat) {
    __shared__ __align__(16) float fused[2304];
    int t = threadIdx.x;  // 64
    for (int i = t; i < 2304; i += 64) fused[i] = x3[i] * attn0[i / 36];
    __syncthreads();
    int row = blockIdx.x * 64 + t;
    const float4* wvv = (const float4*)(lw + (size_t)row * 2304);
    float acc = lb[row];
    for (int i = 0; i < 576; ++i) {
        float4 v = wvv[i];
        const float* f = fused + i * 4;
        acc = fmaf(v.x, f[0], acc);
        acc = fmaf(v.y, f[1], acc);
        acc = fmaf(v.z, f[2], acc);
        acc = fmaf(v.w, f[3], acc);
    }
    feat[row] = fmaxf(acc, 0.0f);
}

// ---------------- LSTM gates ----------------
__global__ void k_lstm_gates(const float* __restrict__ wih, const float* __restrict__ whh,
                             const float* __restrict__ bih, const float* __restrict__ bhh,
                             const float* __restrict__ hx, const float* __restrict__ feat,
                             float* __restrict__ gates) {
    int wid = threadIdx.x >> 6, lane = threadIdx.x & 63;
    int row = blockIdx.x * 4 + wid;
    const float* wi = wih + (size_t)row * 768;
    const float* wh = whh + (size_t)row * 768;
    float acc = 0.0f;
#pragma unroll
    for (int i = 0; i < 12; ++i) {
        int k = lane + i * 64;
        acc = fmaf(wi[k], feat[k & 255], acc);
        acc = fmaf(wh[k], hx[k], acc);
    }
#pragma unroll
    for (int s = 32; s; s >>= 1) acc += __shfl_down(acc, s, 64);
    if (lane == 0) gates[row] = acc + bih[row] + bhh[row];
}

// ---------------- LSTM cell + heads (merged) ----------------
__global__ void k_tail(const float* __restrict__ gates, const float* __restrict__ cx,
                       const float* __restrict__ temb, const int* __restrict__ tx,
                       const float* __restrict__ cw, const float* __restrict__ cb,
                       const float* __restrict__ aw, const float* __restrict__ ab,
                       float* __restrict__ out) {
    __shared__ float z[800];
    int t = threadIdx.x;  // 768
    {
        float g_i = gates[t], g_f = gates[768 + t], g_g = gates[1536 + t], g_o = gates[2304 + t];
        float c = cx[t];
        float cn = sigm(g_f) * c + sigm(g_i) * tanh_f(g_g);
        float hn = sigm(g_o) * tanh_f(cn);
        out[5 + t] = hn;
        out[5 + 768 + t] = cn;
        z[t] = hn;
    }
    if (t < 32) z[768 + t] = temb[tx[0] * 32 + t];
    __syncthreads();
    if (t < 320) {
        int w = t >> 6, lane = t & 63;
        const float* row = (w == 0) ? cw : (aw + (size_t)(w - 1) * 800);
        float acc = 0.0f;
        for (int k = lane; k < 800; k += 64) acc = fmaf(row[k], z[k], acc);
#pragma unroll
        for (int s = 32; s; s >>= 1) acc += __shfl_down(acc, s, 64);
        if (lane == 0) {
            float b = (w == 0) ? cb[0] : ab[w - 1];
            out[w] = acc + b;  // out[0]=critic, out[1..4]=actor
        }
    }
}

extern "C" void kernel_launch(void* const* d_in, const int* in_sizes, int n_in,
                              void* d_out, int out_size, void* d_ws, size_t ws_size,
                              hipStream_t stream) {
    const float* x = (const float*)d_in[0];
    const int* curr = (const int*)d_in[1];
    const int* tx = (const int*)d_in[4];
    const float* hx = (const float*)d_in[5];
    const float* cx = (const float*)d_in[6];
    const float* c1w = (const float*)d_in[7];
    const float* c1b = (const float*)d_in[8];
    const float* c2w = (const float*)d_in[9];
    const float* c2b = (const float*)d_in[10];
    const float* c3w = (const float*)d_in[11];
    const float* c3b = (const float*)d_in[12];
    const float* emb = (const float*)d_in[13];
    const float* temb = (const float*)d_in[14];
    const float* gwih = (const float*)d_in[15];
    const float* gwhh = (const float*)d_in[16];
    const float* gbih = (const float*)d_in[17];
    const float* gbhh = (const float*)d_in[18];
    const float* attw = (const float*)d_in[19];
    const float* attb = (const float*)d_in[20];
    const float* linw = (const float*)d_in[21];
    const float* linb = (const float*)d_in[22];
    const float* lwih = (const float*)d_in[23];
    const float* lwhh = (const float*)d_in[24];
    const float* lbih = (const float*)d_in[25];
    const float* lbhh = (const float*)d_in[26];
    const float* cw = (const float*)d_in[27];
    const float* cb = (const float*)d_in[28];
    const float* aw = (const float*)d_in[29];
    const float* ab = (const float*)d_in[30];
    float* out = (float*)d_out;

    char* ws = (char*)d_ws;
    float* gi = (float*)(ws + 0);  // 2048*768 f32
    float* h1 = (float*)(ws + 6291456);
    float* h2 = (float*)(ws + 6752256);
    float* x3 = (float*)(ws + 6802432);
    float* attn0 = (float*)(ws + 6811648);
    float* feat = (float*)(ws + 6811904);
    float* gates = (float*)(ws + 6812928);

    k_gi<<<6144, 256, 0, stream>>>(curr, emb, gwih, gbih, gbhh, gi);
    k_scan<<<2, 512, 0, stream>>>(gi, gwhh, gbhh, attw, attb, attn0,
                                  x, c1w, c1b, c2w, c2b, c3w, c3b, h1, h2, x3);
    k_feat<<<4, 64, 0, stream>>>(x3, attn0, linw, linb, feat);
    k_lstm_gates<<<768, 256, 0, stream>>>(lwih, lwhh, lbih, lbhh, hx, feat, gates);
    k_tail<<<1, 768, 0, stream>>>(gates, cx, temb, tx, cw, cb, aw, ab, out);
}